// Round 3
// baseline (1033.026 us; speedup 1.0000x reference)
//
#include <hip/hip_runtime.h>

#pragma clang fp contract(off)

#define NB 32
#define NP 2048
#define NT 128
#define BIGF 1e30f

// Exact replication of the reference cost formula (float32, no FMA contraction).
__device__ __forceinline__ float box_cost(float ox0, float oy0, float ox1, float oy1,
                                          float tx0, float ty0, float tx1, float ty1,
                                          float area1, float area2) {
    float l1 = ((fabsf(ox0 - tx0) + fabsf(oy0 - ty0)) + fabsf(ox1 - tx1)) + fabsf(oy1 - ty1);
    float ltx = fmaxf(ox0, tx0), lty = fmaxf(oy0, ty0);
    float rbx = fminf(ox1, tx1), rby = fminf(oy1, ty1);
    float wx = fmaxf(rbx - ltx, 0.0f), wy = fmaxf(rby - lty, 0.0f);
    float inter = wx * wy;
    float uni = (area1 + area2) - inter;
    float iou = inter / (uni + 1e-8f);
    float ex = fmaxf(fmaxf(ox1, tx1) - fminf(ox0, tx0), 0.0f);
    float ey = fmaxf(fmaxf(oy1, ty1) - fminf(oy0, ty0), 0.0f);
    float earea = ex * ey;
    float giou = iou - (earea - uni) / (earea + 1e-8f);
    return l1 - giou;
}

// Phase 1: cost_T[b][t][p] (rows = targets, cols = preds), [NB][NT][NP] f32.
__global__ __launch_bounds__(256) void cost_kernel(const float* __restrict__ ob,
                                                   const float* __restrict__ tb,
                                                   float* __restrict__ cost) {
    int idx = blockIdx.x * 256 + threadIdx.x;
    int b = idx >> 18;
    int t = (idx >> 11) & (NT - 1);
    int p = idx & (NP - 1);
    float4 o = ((const float4*)ob)[b * NP + p];
    float4 g = ((const float4*)tb)[b * NT + t];
    float a1 = (o.z - o.x) * (o.w - o.y);
    float a2 = (g.z - g.x) * (g.w - g.y);
    cost[idx] = box_cost(o.x, o.y, o.z, o.w, g.x, g.y, g.z, g.w, a1, a2);
}

// ---- DPP wave-wide (val, idx) argmin, first-index tie-break ----
#define DPP_ROW_SHR(n) (0x110 | (n))
#define DPP_BCAST15 0x142
#define DPP_BCAST31 0x143

template <int CTRL>
__device__ __forceinline__ void red_step(float& bv, int& bj) {
    int svi = __builtin_amdgcn_update_dpp(0x7149F2CA /* bits of 1e30f */, __float_as_int(bv),
                                          CTRL, 0xF, 0xF, false);
    int sj = __builtin_amdgcn_update_dpp(NP, bj, CTRL, 0xF, 0xF, false);
    float sv = __int_as_float(svi);
    bool take = (sv < bv) || (sv == bv && sj < bj);
    bv = take ? sv : bv;
    bj = take ? sj : bj;
}

__device__ __forceinline__ void wave_argmin(float& bv, int& bj) {
    red_step<DPP_ROW_SHR(1)>(bv, bj);
    red_step<DPP_ROW_SHR(2)>(bv, bj);
    red_step<DPP_ROW_SHR(4)>(bv, bj);
    red_step<DPP_ROW_SHR(8)>(bv, bj);
    red_step<DPP_BCAST15>(bv, bj);
    red_step<DPP_BCAST31>(bv, bj);
    bv = __int_as_float(__builtin_amdgcn_readlane(__float_as_int(bv), 63));
    bj = __builtin_amdgcn_readlane(bj, 63);
}

// Adjacent-pair local tree (contiguous subsets => strict-< keeps smallest index).
#define LOCAL_TREE()                                                                   \
    do {                                                                               \
        _Pragma("unroll") for (int s = 0; s < 32; s += 2) {                            \
            bool t = cv[s + 1] < cv[s];                                                \
            cv[s] = t ? cv[s + 1] : cv[s]; cj[s] = t ? cj[s + 1] : cj[s];              \
        }                                                                              \
        _Pragma("unroll") for (int s = 0; s < 32; s += 4) {                            \
            bool t = cv[s + 2] < cv[s];                                                \
            cv[s] = t ? cv[s + 2] : cv[s]; cj[s] = t ? cj[s + 2] : cj[s];              \
        }                                                                              \
        _Pragma("unroll") for (int s = 0; s < 32; s += 8) {                            \
            bool t = cv[s + 4] < cv[s];                                                \
            cv[s] = t ? cv[s + 4] : cv[s]; cj[s] = t ? cj[s + 4] : cj[s];              \
        }                                                                              \
        _Pragma("unroll") for (int s = 0; s < 32; s += 16) {                           \
            bool t = cv[s + 8] < cv[s];                                                \
            cv[s] = t ? cv[s + 8] : cv[s]; cj[s] = t ? cj[s + 8] : cj[s];              \
        }                                                                              \
        {                                                                              \
            bool t = cv[16] < cv[0];                                                   \
            cv[0] = t ? cv[16] : cv[0]; cj[0] = t ? cj[16] : cj[0];                    \
        }                                                                              \
    } while (0)

#define VC(s) case s: if (lane == ow0) v_r[s] = (v_r[s] + spc_r[s]) - minv; break;

// Phase 2: wave-synchronous JV LSAP. One 64-lane wave per batch.
// Column j: owner lane = (j>>2)&63, slot = ((j>>8)<<2)|(j&3); per-lane j(s) =
// ((s>>2)<<8) | (lane<<2) | (s&3)  (strictly increasing in s for fixed lane).
__global__ __launch_bounds__(64, 1) void solve_wave(const float* __restrict__ cost,
                                                    int* __restrict__ out) {
    __shared__ int row4col[NP];
    __shared__ int col4row[NT];

    const int lane = threadIdx.x;
    const int b = blockIdx.x;
    const float* costb = cost + (size_t)b * NT * NP;

    float pf[32], v_r[32], spc_r[32], cr[32];
    int path_r[32];
    unsigned SCm = 0, pathm = 0;
    float u0 = 0.0f, u1 = 0.0f, pm0 = 0.0f, pm1 = 0.0f;

#pragma unroll
    for (int s = 0; s < 32; ++s) { v_r[s] = 0.0f; path_r[s] = 0; }
    for (int j = lane; j < NP; j += 64) row4col[j] = -1;
    col4row[lane] = -1;
    col4row[lane + 64] = -1;

    {   // prefetch row 0
        const float4* r0 = (const float4*)costb;
#pragma unroll
        for (int g = 0; g < 8; ++g) {
            float4 t = r0[g * 64 + lane];
            pf[g * 4 + 0] = t.x; pf[g * 4 + 1] = t.y;
            pf[g * 4 + 2] = t.z; pf[g * 4 + 3] = t.w;
        }
    }

    for (int i = 0; i < NT; ++i) {
        float cv[32]; int cj[32];
        // ---- fast first pop: cur=i, minv=0, u[i]=0 -> red = pf - v exactly ----
#pragma unroll
        for (int s = 0; s < 32; ++s) {
            spc_r[s] = pf[s] - v_r[s];
            cv[s] = spc_r[s];
            cj[s] = ((s >> 2) << 8) | (lane << 2) | (s & 3);
        }
        // issue next row's prefetch (pf regs free after the subs above)
        if (i + 1 < NT) {
            const float4* nrow = (const float4*)(costb + (size_t)(i + 1) * NP);
#pragma unroll
            for (int g = 0; g < 8; ++g) {
                float4 t = nrow[g * 64 + lane];
                pf[g * 4 + 0] = t.x; pf[g * 4 + 1] = t.y;
                pf[g * 4 + 2] = t.z; pf[g * 4 + 3] = t.w;
            }
        }
        SCm = 0; pathm = 0;
        int sr01 = 0;

        LOCAL_TREE();
        float mv = cv[0]; int mj = cj[0];
        wave_argmin(mv, mj);
        {
            int ow = (mj >> 2) & 63, sl = ((mj >> 8) << 2) | (mj & 3);
            if (lane == ow) SCm |= (1u << sl);
        }
        int npops = 1;
        int r = row4col[mj];

        if (r >= 0) {
            // ---- general shortest-path continuation (rare) ----
            do {
                if ((r & 63) == lane) {
                    if (r < 64) { sr01 |= 1; pm0 = mv; }
                    else        { sr01 |= 2; pm1 = mv; }
                }
                const int cur = r;
                float usel = (cur >= 64) ? u1 : u0;
                float ucur = __int_as_float(
                    __builtin_amdgcn_readlane(__float_as_int(usel), cur & 63));
                const float4* rrow = (const float4*)(costb + (size_t)cur * NP);
#pragma unroll
                for (int g = 0; g < 8; ++g) {
                    float4 t = rrow[g * 64 + lane];
                    cr[g * 4 + 0] = t.x; cr[g * 4 + 1] = t.y;
                    cr[g * 4 + 2] = t.z; cr[g * 4 + 3] = t.w;
                }
#pragma unroll
                for (int s = 0; s < 32; ++s) {
                    float red = ((mv + cr[s]) - ucur) - v_r[s];
                    bool notSC = ((SCm >> s) & 1u) == 0u;
                    bool imp = notSC && (red < spc_r[s]);
                    spc_r[s] = imp ? red : spc_r[s];
                    path_r[s] = imp ? cur : path_r[s];
                    pathm = imp ? (pathm | (1u << s)) : pathm;
                    cv[s] = notSC ? spc_r[s] : BIGF;
                    cj[s] = ((s >> 2) << 8) | (lane << 2) | (s & 3);
                }
                LOCAL_TREE();
                mv = cv[0]; mj = cj[0];
                wave_argmin(mv, mj);
                {
                    int ow = (mj >> 2) & 63, sl = ((mj >> 8) << 2) | (mj & 3);
                    if (lane == ow) SCm |= (1u << sl);
                }
                ++npops;
                r = row4col[mj];
            } while (r >= 0);
        }

        const int sink = mj;
        const float minv = mv;

        // ---- dual updates (exact reference order) ----
        if ((i & 63) == lane) { if (i < 64) u0 = u0 + minv; else u1 = u1 + minv; }
        if (sr01 & 1) u0 = (u0 + minv) - pm0;
        if (sr01 & 2) u1 = (u1 + minv) - pm1;

        if (npops == 1) {
            // SC = {sink}; path[sink] = i implicitly
            const int ow0 = (sink >> 2) & 63;
            const int sl0 = ((sink >> 8) << 2) | (sink & 3);
            switch (sl0) {
                VC(0) VC(1) VC(2) VC(3) VC(4) VC(5) VC(6) VC(7)
                VC(8) VC(9) VC(10) VC(11) VC(12) VC(13) VC(14) VC(15)
                VC(16) VC(17) VC(18) VC(19) VC(20) VC(21) VC(22) VC(23)
                VC(24) VC(25) VC(26) VC(27) VC(28) VC(29) VC(30) VC(31)
            }
            if (lane == 0) { row4col[sink] = i; col4row[i] = sink; }
        } else {
#pragma unroll
            for (int s = 0; s < 32; ++s) {
                if ((SCm >> s) & 1u) v_r[s] = (v_r[s] + spc_r[s]) - minv;
            }
            // augment along alternating path
            int j = sink;
            while (true) {
                int sl = ((j >> 8) << 2) | (j & 3);
                int ow = (j >> 2) & 63;
                int pv = ((pathm >> 0) & 1u) ? path_r[0] : i;
#pragma unroll
                for (int s = 1; s < 32; ++s) {
                    int leaf = ((pathm >> s) & 1u) ? path_r[s] : i;
                    pv = (sl == s) ? leaf : pv;
                }
                int ii = __shfl(pv, ow);
                if (lane == 0) row4col[j] = ii;
                int nj = col4row[ii];
                if (lane == 0) col4row[ii] = j;
                if (ii == i) break;
                j = nj;
            }
        }
    }

    // output: sort targets by assigned pred index (all distinct)
    for (int t = lane; t < NT; t += 64) {
        int c = col4row[t];
        int rank = 0;
        for (int t2 = 0; t2 < NT; ++t2) rank += (col4row[t2] < c) ? 1 : 0;
        out[(b * 2 + 0) * NT + rank] = c;
        out[(b * 2 + 1) * NT + rank] = t;
    }
}

// Fallback (ws too small): LDS-based block solver computing costs on the fly.
__global__ __launch_bounds__(512) void solve_fallback(const float* __restrict__ ob,
                                                      const float* __restrict__ tb,
                                                      int* __restrict__ out) {
    __shared__ float v[NP], spc[NP];
    __shared__ int path[NP], row4col[NP];
    __shared__ unsigned char SC[NP];
    __shared__ float u[NT];
    __shared__ int col4row[NT];
    __shared__ unsigned char SR[NT];
    __shared__ float rv[8];
    __shared__ int ri[8];
    __shared__ int s_cur, s_sink;
    __shared__ float s_minv;
    __shared__ float px0[NP], py0[NP], px1[NP], py1[NP], pa[NP];
    __shared__ float tx0[NT], ty0[NT], tx1[NT], ty1[NT], ta[NT];

    const int tid = threadIdx.x;
    const int b = blockIdx.x;

    for (int j = tid; j < NP; j += 512) {
        v[j] = 0.0f; row4col[j] = -1;
        float4 o = ((const float4*)ob)[b * NP + j];
        px0[j] = o.x; py0[j] = o.y; px1[j] = o.z; py1[j] = o.w;
        pa[j] = (o.z - o.x) * (o.w - o.y);
    }
    for (int t = tid; t < NT; t += 512) {
        u[t] = 0.0f; col4row[t] = -1;
        float4 g = ((const float4*)tb)[b * NT + t];
        tx0[t] = g.x; ty0[t] = g.y; tx1[t] = g.z; ty1[t] = g.w;
        ta[t] = (g.z - g.x) * (g.w - g.y);
    }
    __syncthreads();

    for (int i = 0; i < NT; ++i) {
        for (int j = tid; j < NP; j += 512) { spc[j] = BIGF; SC[j] = 0; }
        for (int t = tid; t < NT; t += 512) SR[t] = 0;
        if (tid == 0) { s_cur = i; s_minv = 0.0f; s_sink = -1; }
        __syncthreads();

        while (s_sink < 0) {
            const int cur = s_cur;
            const float minv = s_minv;
            if (tid == 0) SR[cur] = 1;
            const float ucur = u[cur];
            float c0 = tx0[cur], c1 = ty0[cur], c2 = tx1[cur], c3 = ty1[cur], ca = ta[cur];
            float bv = BIGF;
            int bi = NP;
            for (int k = 0; k < NP / 512; ++k) {
                int j = tid + k * 512;
                float cj = box_cost(px0[j], py0[j], px1[j], py1[j], c0, c1, c2, c3, pa[j], ca);
                float cand;
                if (!SC[j]) {
                    float red = ((minv + cj) - ucur) - v[j];
                    if (red < spc[j]) { spc[j] = red; path[j] = cur; }
                    cand = spc[j];
                } else {
                    cand = BIGF;
                }
                if (cand < bv || (cand == bv && j < bi)) { bv = cand; bi = j; }
            }
            for (int off = 32; off >= 1; off >>= 1) {
                float ov = __shfl_xor(bv, off);
                int oi = __shfl_xor(bi, off);
                if (ov < bv || (ov == bv && oi < bi)) { bv = ov; bi = oi; }
            }
            if ((tid & 63) == 0) { rv[tid >> 6] = bv; ri[tid >> 6] = bi; }
            __syncthreads();
            if (tid == 0) {
                float mvv = rv[0]; int mjj = ri[0];
                for (int w = 1; w < 8; ++w)
                    if (rv[w] < mvv || (rv[w] == mvv && ri[w] < mjj)) { mvv = rv[w]; mjj = ri[w]; }
                s_minv = mvv;
                SC[mjj] = 1;
                int rr = row4col[mjj];
                if (rr < 0) s_sink = mjj; else s_cur = rr;
            }
            __syncthreads();
        }

        const float minv = s_minv;
        const int sink = s_sink;
        for (int j = tid; j < NP; j += 512) if (SC[j]) v[j] = (v[j] + spc[j]) - minv;
        for (int t = tid; t < NT; t += 512) {
            if (t == i) u[t] = u[t] + minv;
            else if (SR[t]) u[t] = (u[t] + minv) - spc[col4row[t]];
        }
        __syncthreads();
        if (tid == 0) {
            int j = sink;
            while (true) {
                int ii = path[j];
                row4col[j] = ii;
                int nj = col4row[ii];
                col4row[ii] = j;
                if (ii == i) break;
                j = nj;
            }
        }
        __syncthreads();
    }

    if (tid < NT) {
        int c = col4row[tid];
        int rank = 0;
        for (int t2 = 0; t2 < NT; ++t2) rank += (col4row[t2] < c) ? 1 : 0;
        out[(b * 2 + 0) * NT + rank] = c;
        out[(b * 2 + 1) * NT + rank] = tid;
    }
}

extern "C" void kernel_launch(void* const* d_in, const int* in_sizes, int n_in,
                              void* d_out, int out_size, void* d_ws, size_t ws_size,
                              hipStream_t stream) {
    const float* ob = (const float*)d_in[0];   // [32, 2048, 4] f32
    const float* tb = (const float*)d_in[1];   // [32, 128, 4] f32
    int* out = (int*)d_out;                    // [32, 2, 128] int32

    const size_t need = (size_t)NB * NT * NP * sizeof(float);  // 32 MB
    if (ws_size >= need) {
        float* cost = (float*)d_ws;
        cost_kernel<<<(NB * NT * NP) / 256, 256, 0, stream>>>(ob, tb, cost);
        solve_wave<<<NB, 64, 0, stream>>>(cost, out);
    } else {
        solve_fallback<<<NB, 512, 0, stream>>>(ob, tb, out);
    }
}

// Round 4
// 214.363 us; speedup vs baseline: 4.8190x; 4.8190x over previous
//
#include <hip/hip_runtime.h>

#pragma clang fp contract(off)

#define NB 32
#define NP 2048
#define NT 128
#define BIGF 1e30f

// Exact replication of the reference cost formula (float32, no FMA contraction).
__device__ __forceinline__ float box_cost(float ox0, float oy0, float ox1, float oy1,
                                          float tx0, float ty0, float tx1, float ty1,
                                          float area1, float area2) {
    float l1 = ((fabsf(ox0 - tx0) + fabsf(oy0 - ty0)) + fabsf(ox1 - tx1)) + fabsf(oy1 - ty1);
    float ltx = fmaxf(ox0, tx0), lty = fmaxf(oy0, ty0);
    float rbx = fminf(ox1, tx1), rby = fminf(oy1, ty1);
    float wx = fmaxf(rbx - ltx, 0.0f), wy = fmaxf(rby - lty, 0.0f);
    float inter = wx * wy;
    float uni = (area1 + area2) - inter;
    float iou = inter / (uni + 1e-8f);
    float ex = fmaxf(fmaxf(ox1, tx1) - fminf(ox0, tx0), 0.0f);
    float ey = fmaxf(fmaxf(oy1, ty1) - fminf(oy0, ty0), 0.0f);
    float earea = ex * ey;
    float giou = iou - (earea - uni) / (earea + 1e-8f);
    return l1 - giou;
}

// Phase 1: cost_T[b][t][p] (rows = targets, cols = preds), [NB][NT][NP] f32.
__global__ __launch_bounds__(256) void cost_kernel(const float* __restrict__ ob,
                                                   const float* __restrict__ tb,
                                                   float* __restrict__ cost) {
    int idx = blockIdx.x * 256 + threadIdx.x;
    int b = idx >> 18;
    int t = (idx >> 11) & (NT - 1);
    int p = idx & (NP - 1);
    float4 o = ((const float4*)ob)[b * NP + p];
    float4 g = ((const float4*)tb)[b * NT + t];
    float a1 = (o.z - o.x) * (o.w - o.y);
    float a2 = (g.z - g.x) * (g.w - g.y);
    cost[idx] = box_cost(o.x, o.y, o.z, o.w, g.x, g.y, g.z, g.w, a1, a2);
}

// ---- DPP wave-wide (val, idx) argmin, first-index tie-break ----
#define DPP_ROW_SHR(n) (0x110 | (n))
#define DPP_BCAST15 0x142
#define DPP_BCAST31 0x143

template <int CTRL>
__device__ __forceinline__ void red_step(float& bv, int& bj) {
    int svi = __builtin_amdgcn_update_dpp(0x7149F2CA /* bits of 1e30f */, __float_as_int(bv),
                                          CTRL, 0xF, 0xF, false);
    int sj = __builtin_amdgcn_update_dpp(NP, bj, CTRL, 0xF, 0xF, false);
    float sv = __int_as_float(svi);
    bool take = (sv < bv) || (sv == bv && sj < bj);
    bv = take ? sv : bv;
    bj = take ? sj : bj;
}

__device__ __forceinline__ void wave_argmin(float& bv, int& bj) {
    red_step<DPP_ROW_SHR(1)>(bv, bj);
    red_step<DPP_ROW_SHR(2)>(bv, bj);
    red_step<DPP_ROW_SHR(4)>(bv, bj);
    red_step<DPP_ROW_SHR(8)>(bv, bj);
    red_step<DPP_BCAST15>(bv, bj);
    red_step<DPP_BCAST31>(bv, bj);
    bv = __int_as_float(__builtin_amdgcn_readlane(__float_as_int(bv), 63));
    bj = __builtin_amdgcn_readlane(bj, 63);
}

// Phase 2: wave-synchronous JV LSAP. One 64-lane wave per batch.
// Column j: owner lane = (j>>2)&63, slot = ((j>>8)<<2)|(j&3); per-lane j(s) =
// ((s>>2)<<8) | (lane<<2) | (s&3)  (strictly increasing in s for fixed lane).
__global__ __launch_bounds__(64) void solve_wave(const float* __restrict__ cost,
                                                 int* __restrict__ out) {
    __shared__ int row4col[NP];
    __shared__ int col4row[NT];

    const int lane = threadIdx.x;
    const int lane4 = lane << 2;
    const int b = blockIdx.x;
    const float* costb = cost + (size_t)b * NT * NP;

    float pf[32], v_r[32], spc_r[32], cr[32];
    int path_r[32];
    float u0 = 0.0f, u1 = 0.0f, pm0 = 0.0f, pm1 = 0.0f;

#pragma unroll
    for (int s = 0; s < 32; ++s) { v_r[s] = 0.0f; path_r[s] = 0; }
    for (int j = lane; j < NP; j += 64) row4col[j] = -1;
    col4row[lane] = -1;
    col4row[lane + 64] = -1;

    {   // prefetch row 0
        const float4* r0 = (const float4*)costb;
#pragma unroll
        for (int g = 0; g < 8; ++g) {
            float4 t = r0[g * 64 + lane];
            pf[g * 4 + 0] = t.x; pf[g * 4 + 1] = t.y;
            pf[g * 4 + 2] = t.z; pf[g * 4 + 3] = t.w;
        }
    }

    for (int i = 0; i < NT; ++i) {
        unsigned SCm = 0, pathm = 0;
        int sr01 = 0;

        // ---- fast first pop: cur=i, minv=0, u[i]=0 -> red = pf - v exactly ----
        float bv = BIGF;
        int bj = NP;
#pragma unroll
        for (int s = 0; s < 32; ++s) {
            float sp = pf[s] - v_r[s];
            spc_r[s] = sp;
            int j = (((s >> 2) << 8) | (s & 3)) | lane4;
            if (sp < bv) { bv = sp; bj = j; }
        }
        // issue next row's prefetch (pf regs dead after the subs above)
        if (i + 1 < NT) {
            const float4* nrow = (const float4*)(costb + (size_t)(i + 1) * NP);
#pragma unroll
            for (int g = 0; g < 8; ++g) {
                float4 t = nrow[g * 64 + lane];
                pf[g * 4 + 0] = t.x; pf[g * 4 + 1] = t.y;
                pf[g * 4 + 2] = t.z; pf[g * 4 + 3] = t.w;
            }
        }
        wave_argmin(bv, bj);
        float mv = bv;
        int mj = bj;
        if (((mj >> 2) & 63) == lane) SCm |= (1u << (((mj >> 8) << 2) | (mj & 3)));
        int npops = 1;
        int r = row4col[mj];

        if (r >= 0) {
            // ---- general shortest-path continuation ----
            do {
                if ((r & 63) == lane) {
                    if (r < 64) { sr01 |= 1; pm0 = mv; }
                    else        { sr01 |= 2; pm1 = mv; }
                }
                const int cur = r;
                float usel = (cur >= 64) ? u1 : u0;
                float ucur = __int_as_float(
                    __builtin_amdgcn_readlane(__float_as_int(usel), cur & 63));
                const float4* rrow = (const float4*)(costb + (size_t)cur * NP);
#pragma unroll
                for (int g = 0; g < 8; ++g) {
                    float4 t = rrow[g * 64 + lane];
                    cr[g * 4 + 0] = t.x; cr[g * 4 + 1] = t.y;
                    cr[g * 4 + 2] = t.z; cr[g * 4 + 3] = t.w;
                }
                bv = BIGF;
                bj = NP;
#pragma unroll
                for (int s = 0; s < 32; ++s) {
                    float red = ((mv + cr[s]) - ucur) - v_r[s];
                    bool notSC = ((SCm >> s) & 1u) == 0u;
                    bool imp = notSC && (red < spc_r[s]);
                    spc_r[s] = imp ? red : spc_r[s];
                    path_r[s] = imp ? cur : path_r[s];
                    pathm = imp ? (pathm | (1u << s)) : pathm;
                    float cand = notSC ? spc_r[s] : BIGF;
                    int j = (((s >> 2) << 8) | (s & 3)) | lane4;
                    if (cand < bv) { bv = cand; bj = j; }
                }
                wave_argmin(bv, bj);
                mv = bv;
                mj = bj;
                if (((mj >> 2) & 63) == lane) SCm |= (1u << (((mj >> 8) << 2) | (mj & 3)));
                ++npops;
                r = row4col[mj];
            } while (r >= 0);
        }

        const int sink = mj;
        const float minv = mv;

        // ---- dual updates (exact reference order) ----
        if ((i & 63) == lane) { if (i < 64) u0 = u0 + minv; else u1 = u1 + minv; }
        if (sr01 & 1) u0 = (u0 + minv) - pm0;
        if (sr01 & 2) u1 = (u1 + minv) - pm1;
#pragma unroll
        for (int s = 0; s < 32; ++s) {
            if ((SCm >> s) & 1u) v_r[s] = (v_r[s] + spc_r[s]) - minv;
        }

        // ---- augment ----
        if (npops == 1) {
            // SC = {sink}; path[sink] = i implicitly
            if (lane == 0) { row4col[sink] = i; col4row[i] = sink; }
        } else {
            int j = sink;
            while (true) {
                int sl = ((j >> 8) << 2) | (j & 3);
                int ow = (j >> 2) & 63;
                int pv = ((pathm >> 0) & 1u) ? path_r[0] : i;
#pragma unroll
                for (int s = 1; s < 32; ++s) {
                    int leaf = ((pathm >> s) & 1u) ? path_r[s] : i;
                    pv = (sl == s) ? leaf : pv;
                }
                int ii = __shfl(pv, ow);
                if (lane == 0) row4col[j] = ii;
                int nj = col4row[ii];
                if (lane == 0) col4row[ii] = j;
                if (ii == i) break;
                j = nj;
            }
        }
    }

    // output: sort targets by assigned pred index (all distinct)
    for (int t = lane; t < NT; t += 64) {
        int c = col4row[t];
        int rank = 0;
        for (int t2 = 0; t2 < NT; ++t2) rank += (col4row[t2] < c) ? 1 : 0;
        out[(b * 2 + 0) * NT + rank] = c;
        out[(b * 2 + 1) * NT + rank] = t;
    }
}

// Fallback (ws too small): LDS-based block solver computing costs on the fly.
__global__ __launch_bounds__(512) void solve_fallback(const float* __restrict__ ob,
                                                      const float* __restrict__ tb,
                                                      int* __restrict__ out) {
    __shared__ float v[NP], spc[NP];
    __shared__ int path[NP], row4col[NP];
    __shared__ unsigned char SC[NP];
    __shared__ float u[NT];
    __shared__ int col4row[NT];
    __shared__ unsigned char SR[NT];
    __shared__ float rv[8];
    __shared__ int ri[8];
    __shared__ int s_cur, s_sink;
    __shared__ float s_minv;
    __shared__ float px0[NP], py0[NP], px1[NP], py1[NP], pa[NP];
    __shared__ float tx0[NT], ty0[NT], tx1[NT], ty1[NT], ta[NT];

    const int tid = threadIdx.x;
    const int b = blockIdx.x;

    for (int j = tid; j < NP; j += 512) {
        v[j] = 0.0f; row4col[j] = -1;
        float4 o = ((const float4*)ob)[b * NP + j];
        px0[j] = o.x; py0[j] = o.y; px1[j] = o.z; py1[j] = o.w;
        pa[j] = (o.z - o.x) * (o.w - o.y);
    }
    for (int t = tid; t < NT; t += 512) {
        u[t] = 0.0f; col4row[t] = -1;
        float4 g = ((const float4*)tb)[b * NT + t];
        tx0[t] = g.x; ty0[t] = g.y; tx1[t] = g.z; ty1[t] = g.w;
        ta[t] = (g.z - g.x) * (g.w - g.y);
    }
    __syncthreads();

    for (int i = 0; i < NT; ++i) {
        for (int j = tid; j < NP; j += 512) { spc[j] = BIGF; SC[j] = 0; }
        for (int t = tid; t < NT; t += 512) SR[t] = 0;
        if (tid == 0) { s_cur = i; s_minv = 0.0f; s_sink = -1; }
        __syncthreads();

        while (s_sink < 0) {
            const int cur = s_cur;
            const float minv = s_minv;
            if (tid == 0) SR[cur] = 1;
            const float ucur = u[cur];
            float c0 = tx0[cur], c1 = ty0[cur], c2 = tx1[cur], c3 = ty1[cur], ca = ta[cur];
            float bv = BIGF;
            int bi = NP;
            for (int k = 0; k < NP / 512; ++k) {
                int j = tid + k * 512;
                float cj = box_cost(px0[j], py0[j], px1[j], py1[j], c0, c1, c2, c3, pa[j], ca);
                float cand;
                if (!SC[j]) {
                    float red = ((minv + cj) - ucur) - v[j];
                    if (red < spc[j]) { spc[j] = red; path[j] = cur; }
                    cand = spc[j];
                } else {
                    cand = BIGF;
                }
                if (cand < bv || (cand == bv && j < bi)) { bv = cand; bi = j; }
            }
            for (int off = 32; off >= 1; off >>= 1) {
                float ov = __shfl_xor(bv, off);
                int oi = __shfl_xor(bi, off);
                if (ov < bv || (ov == bv && oi < bi)) { bv = ov; bi = oi; }
            }
            if ((tid & 63) == 0) { rv[tid >> 6] = bv; ri[tid >> 6] = bi; }
            __syncthreads();
            if (tid == 0) {
                float mvv = rv[0]; int mjj = ri[0];
                for (int w = 1; w < 8; ++w)
                    if (rv[w] < mvv || (rv[w] == mvv && ri[w] < mjj)) { mvv = rv[w]; mjj = ri[w]; }
                s_minv = mvv;
                SC[mjj] = 1;
                int rr = row4col[mjj];
                if (rr < 0) s_sink = mjj; else s_cur = rr;
            }
            __syncthreads();
        }

        const float minv = s_minv;
        const int sink = s_sink;
        for (int j = tid; j < NP; j += 512) if (SC[j]) v[j] = (v[j] + spc[j]) - minv;
        for (int t = tid; t < NT; t += 512) {
            if (t == i) u[t] = u[t] + minv;
            else if (SR[t]) u[t] = (u[t] + minv) - spc[col4row[t]];
        }
        __syncthreads();
        if (tid == 0) {
            int j = sink;
            while (true) {
                int ii = path[j];
                row4col[j] = ii;
                int nj = col4row[ii];
                col4row[ii] = j;
                if (ii == i) break;
                j = nj;
            }
        }
        __syncthreads();
    }

    if (tid < NT) {
        int c = col4row[tid];
        int rank = 0;
        for (int t2 = 0; t2 < NT; ++t2) rank += (col4row[t2] < c) ? 1 : 0;
        out[(b * 2 + 0) * NT + rank] = c;
        out[(b * 2 + 1) * NT + rank] = tid;
    }
}

extern "C" void kernel_launch(void* const* d_in, const int* in_sizes, int n_in,
                              void* d_out, int out_size, void* d_ws, size_t ws_size,
                              hipStream_t stream) {
    const float* ob = (const float*)d_in[0];   // [32, 2048, 4] f32
    const float* tb = (const float*)d_in[1];   // [32, 128, 4] f32
    int* out = (int*)d_out;                    // [32, 2, 128] int32

    const size_t need = (size_t)NB * NT * NP * sizeof(float);  // 32 MB
    if (ws_size >= need) {
        float* cost = (float*)d_ws;
        cost_kernel<<<(NB * NT * NP) / 256, 256, 0, stream>>>(ob, tb, cost);
        solve_wave<<<NB, 64, 0, stream>>>(cost, out);
    } else {
        solve_fallback<<<NB, 512, 0, stream>>>(ob, tb, out);
    }
}